// Round 11
// baseline (642.327 us; speedup 1.0000x reference)
//
#include <hip/hip_runtime.h>
#include <hip/hip_bf16.h>

#define EPS 1e-5f

typedef unsigned short u16;
typedef unsigned int u32;
typedef __attribute__((ext_vector_type(8))) short bf16x8;
typedef __attribute__((ext_vector_type(4))) float f32x4;

// ---- bf16 helpers (RNE encode, shift decode) ----
__device__ __forceinline__ u32 f2bf(float f) {
  u32 u = __float_as_uint(f);
  return (u + 0x7FFFu + ((u >> 16) & 1u)) >> 16;
}
__device__ __forceinline__ u32 pack2bf(float lo, float hi) {
  return f2bf(lo) | (f2bf(hi) << 16);
}

// accumulate 2 packed bf16 into float2 accumulator
__device__ __forceinline__ void dacc(float2& a, u32 u) {
  a.x += __uint_as_float(u << 16);
  a.y += __uint_as_float(u & 0xFFFF0000u);
}

// ---------------- CSR build: histogram + per-edge rank (8 edges/thread) ----------------
// NOTE: at the device-scope atomic-transaction wall (~24 G/s, 56 MB memory-side
// traffic) — measured invariant under ILP depth 4->8 (R8/R10). Do not touch.
__global__ void k_hist_rank(const int* __restrict__ dst, int* __restrict__ cnt,
                            int* __restrict__ rank, int E) {
  int i = blockIdx.x * blockDim.x + threadIdx.x;
  int i8 = i << 3;
  if (i8 + 7 < E) {
    int4 da = *(const int4*)(dst + i8);
    int4 db = *(const int4*)(dst + i8 + 4);
    int r0 = atomicAdd(&cnt[da.x], 1);
    int r1 = atomicAdd(&cnt[da.y], 1);
    int r2 = atomicAdd(&cnt[da.z], 1);
    int r3 = atomicAdd(&cnt[da.w], 1);
    int r4 = atomicAdd(&cnt[db.x], 1);
    int r5 = atomicAdd(&cnt[db.y], 1);
    int r6 = atomicAdd(&cnt[db.z], 1);
    int r7 = atomicAdd(&cnt[db.w], 1);
    *(int4*)(rank + i8)     = make_int4(r0, r1, r2, r3);
    *(int4*)(rank + i8 + 4) = make_int4(r4, r5, r6, r7);
  } else {
    for (int e = i8; e < E; ++e) rank[e] = atomicAdd(&cnt[dst[e]], 1);
  }
}

// fused: dis, pdeg, and xs = dis * x (padded 13->16, row N zeroed)
__global__ void k_prep_nodes(const int* __restrict__ cnt, const float* __restrict__ x,
                             float* __restrict__ dis, int* __restrict__ pdeg,
                             float* __restrict__ xs, int N) {
  int n = blockIdx.x * blockDim.x + threadIdx.x;
  if (n > N) return;
  if (n == N) {
#pragma unroll
    for (int f = 0; f < 16; f += 4)
      *(float4*)(xs + (size_t)N * 16 + f) = make_float4(0.f, 0.f, 0.f, 0.f);
    return;
  }
  int d = cnt[n];
  float dn = rsqrtf((float)d + 1.0f);
  dis[n] = dn;
  pdeg[n] = (d + 3) & ~3;
  float v[16];
#pragma unroll
  for (int f = 0; f < 13; ++f) v[f] = x[(size_t)n * 13 + f] * dn;
  v[13] = v[14] = v[15] = 0.f;
#pragma unroll
  for (int f = 0; f < 16; f += 4)
    *(float4*)(xs + (size_t)n * 16 + f) = make_float4(v[f], v[f+1], v[f+2], v[f+3]);
}

__global__ void k_scan_block(const int* __restrict__ in, int* __restrict__ out,
                             int* __restrict__ bsum, int N) {
  __shared__ int tmp[256];
  int lid = threadIdx.x;
  int i = blockIdx.x * 256 + lid;
  int v = (i < N) ? in[i] : 0;
  tmp[lid] = v;
  __syncthreads();
  for (int off = 1; off < 256; off <<= 1) {
    int t = (lid >= off) ? tmp[lid - off] : 0;
    __syncthreads();
    tmp[lid] += t;
    __syncthreads();
  }
  if (i < N) out[i] = tmp[lid] - v;            // exclusive within block
  if (lid == 255) bsum[blockIdx.x] = tmp[255];
}

__global__ void k_scan_bsum(const int* __restrict__ bsum, int* __restrict__ bexc, int nb) {
  __shared__ int tmp[512];
  int lid = threadIdx.x;
  int v = (lid < nb) ? bsum[lid] : 0;
  tmp[lid] = v;
  __syncthreads();
  for (int off = 1; off < 512; off <<= 1) {
    int t = (lid >= off) ? tmp[lid - off] : 0;
    __syncthreads();
    tmp[lid] += t;
    __syncthreads();
  }
  if (lid < nb) bexc[lid] = tmp[lid] - v;      // exclusive
}

// fused: finalize offs + fill dummy pad slots (disjoint from real slots, order-free)
__global__ void k_add_back_pad(int* __restrict__ offs, const int* __restrict__ bexc,
                               const int* __restrict__ bsum, const int* __restrict__ deg,
                               const int* __restrict__ pdeg, int* __restrict__ csr,
                               int N, int nb) {
  int i = blockIdx.x * 256 + threadIdx.x;
  if (i < N) {
    int o = offs[i] + bexc[blockIdx.x];
    offs[i] = o;
    int b = o + deg[i], e = o + pdeg[i];
    for (int j = b; j < e; ++j) csr[j] = N;
  }
  if (i == 0) offs[N] = bexc[nb - 1] + bsum[nb - 1];   // total padded count
}

// slot = offs[dst] + rank  (no atomic; scatter store is fire-and-forget)
__global__ void k_fill_rank(const int* __restrict__ src, const int* __restrict__ dst,
                            const int* __restrict__ rank, const int* __restrict__ offs,
                            int* __restrict__ csr, int E) {
  int i = blockIdx.x * blockDim.x + threadIdx.x;
  int i4 = i << 2;
  if (i4 + 3 < E) {
    int s0 = src[i4], s1 = src[i4 + 1], s2 = src[i4 + 2], s3 = src[i4 + 3];
    int d0 = dst[i4], d1 = dst[i4 + 1], d2 = dst[i4 + 2], d3 = dst[i4 + 3];
    int r0 = rank[i4], r1 = rank[i4 + 1], r2 = rank[i4 + 2], r3 = rank[i4 + 3];
    csr[offs[d0] + r0] = s0;
    csr[offs[d1] + r1] = s1;
    csr[offs[d2] + r2] = s2;
    csr[offs[d3] + r3] = s3;
  } else {
    for (int e = i4; e < E; ++e) csr[offs[dst[e]] + rank[e]] = src[e];
  }
}

// ---------------- W prep: split-transpose to bf16 hi/lo + BN scale fold ----------------
// Also zeroes deg, pooled, and the pad row of hbf2 (replaces hipMemsetAsync).
__global__ void k_prep_w(const float* __restrict__ W2, const float* __restrict__ W3,
                         const float* __restrict__ b2, const float* __restrict__ g2,
                         const float* __restrict__ be2, const float* __restrict__ m2,
                         const float* __restrict__ v2,
                         const float* __restrict__ b3, const float* __restrict__ g3,
                         const float* __restrict__ be3, const float* __restrict__ m3,
                         const float* __restrict__ v3,
                         u16* __restrict__ Wht2, u16* __restrict__ Wlt2,
                         u16* __restrict__ Wht3, u16* __restrict__ Wlt3,
                         float* __restrict__ sc2, float* __restrict__ tc2,
                         float* __restrict__ sc3, float* __restrict__ tc3,
                         int* __restrict__ deg, float* __restrict__ pooled,
                         u32* __restrict__ hbf2_padrow, int N, int GP) {
  int idx = blockIdx.x * 256 + threadIdx.x;     // 0..32767
  int layer = idx >> 14;
  int e = idx & 16383;
  int c = e >> 7, k = e & 127;
  const float* W = layer ? W3 : W2;
  float w = W[k * 128 + c];                     // transpose read
  u32 h = f2bf(w);
  float l = w - __uint_as_float(h << 16);
  u16* Wh = layer ? Wht3 : Wht2;
  u16* Wl = layer ? Wlt3 : Wlt2;
  Wh[e] = (u16)h;                               // [c][k] layout
  Wl[e] = (u16)f2bf(l);
  if (e < 128) {
    int ch = e;
    const float* gg = layer ? g3 : g2;  const float* vv = layer ? v3 : v2;
    const float* be = layer ? be3 : be2; const float* mm = layer ? m3 : m2;
    const float* bb = layer ? b3 : b2;
    float s = gg[ch] * rsqrtf(vv[ch] + EPS);
    (layer ? sc3 : sc2)[ch] = s;
    (layer ? tc3 : tc2)[ch] = be[ch] + (bb[ch] - mm[ch]) * s;
  }
  for (int i = idx; i < N; i += 32768) deg[i] = 0;
  for (int i = idx; i < GP; i += 32768) pooled[i] = 0.f;
  if (idx < 64) hbf2_padrow[idx] = 0u;          // zero pad row (128 bf16)
}

// agg[d] = dis[d] * (sum_{s in padded N(d)} xs[s] + xs[d]); exact 4-edge steps
__global__ __launch_bounds__(64) void k_agg16(
    const float* __restrict__ xs, const int* __restrict__ csr,
    const int* __restrict__ offs, const float* __restrict__ dis,
    float* __restrict__ out, int N) {
  int node = (blockIdx.x << 2) + (threadIdx.x >> 4);
  if (node >= N) return;
  int f = threadIdx.x & 15;
  float a0 = xs[(size_t)node * 16 + f];   // self, weight 1
  float a1 = 0.f, a2 = 0.f, a3 = 0.f;
  int beg = offs[node], end = offs[node + 1];
  for (int i = beg; i < end; i += 4) {
    int4 s4 = *(const int4*)(csr + i);
    a0 += xs[(size_t)s4.x * 16 + f];
    a1 += xs[(size_t)s4.y * 16 + f];
    a2 += xs[(size_t)s4.z * 16 + f];
    a3 += xs[(size_t)s4.w * 16 + f];
  }
  out[(size_t)node * 16 + f] = dis[node] * ((a0 + a1) + (a2 + a3));
}

// K=13 GEMM + BN/ReLU, hs1 = dis*h1 bf16. Wave owns 128 channels (2/lane).
__global__ __launch_bounds__(256) void k_gemm1(
    const float* __restrict__ ax, const float* __restrict__ W1,
    const float* __restrict__ bb, const float* __restrict__ gg,
    const float* __restrict__ be, const float* __restrict__ mm,
    const float* __restrict__ vv, const float* __restrict__ dis,
    u32* __restrict__ outb, int N) {
  const int lane = threadIdx.x & 63;
  const int wid = blockIdx.x * (blockDim.x >> 6) + (threadIdx.x >> 6);
  const int nw = gridDim.x * (blockDim.x >> 6);
  const int c0 = lane * 2, c1 = c0 + 1;
  float s0 = gg[c0] * rsqrtf(vv[c0] + EPS);
  float t0 = be[c0] + (bb[c0] - mm[c0]) * s0;
  float s1 = gg[c1] * rsqrtf(vv[c1] + EPS);
  float t1 = be[c1] + (bb[c1] - mm[c1]) * s1;
  float w0[13], w1[13];
#pragma unroll
  for (int k = 0; k < 13; ++k) {
    w0[k] = W1[k * 128 + c0];
    w1[k] = W1[k * 128 + c1];
  }
  for (int node = wid; node <= N; node += nw) {
    if (node == N) { outb[(size_t)node * 64 + lane] = 0u; continue; }
    float4 A0 = *(const float4*)(ax + (size_t)node * 16);
    float4 A1 = *(const float4*)(ax + (size_t)node * 16 + 4);
    float4 A2 = *(const float4*)(ax + (size_t)node * 16 + 8);
    float  a12 = ax[(size_t)node * 16 + 12];
    float av[13] = {A0.x, A0.y, A0.z, A0.w, A1.x, A1.y, A1.z, A1.w,
                    A2.x, A2.y, A2.z, A2.w, a12};
    float acc0 = 0.f, acc1 = 0.f;
#pragma unroll
    for (int k = 0; k < 13; ++k) {
      acc0 = fmaf(av[k], w0[k], acc0);
      acc1 = fmaf(av[k], w1[k], acc1);
    }
    float dn = dis[node];
    float o0 = dn * fmaxf(fmaf(acc0, s0, t0), 0.f);
    float o1 = dn * fmaxf(fmaf(acc1, s1, t1), 0.f);
    outb[(size_t)node * 64 + lane] = pack2bf(o0, o1);
  }
}

// ---- FUSED: 128-feat aggregation (quad scheme) -> LDS -> bf16x3 MFMA GEMM ----
// Block = 4 waves, 64 rows. Phase 1: wave wv aggregates rows [wv*16, wv*16+16)
// into XOR-swizzled LDS (hi+lo bf16 split). Phase 2: wave wv GEMMs its 16 rows.
// IN and OUT must be different buffers (other blocks still gather from IN).
// MODE 0: out = bf16(dis*relu(...));  MODE 1: out = bf16(relu(...)).
template <int MODE>
__global__ __launch_bounds__(256) void k_agg_gemm(
    const u16* __restrict__ hb, const int* __restrict__ csr,
    const int* __restrict__ offs, const float* __restrict__ dis,
    const u16* __restrict__ Wht, const u16* __restrict__ Wlt,
    const float* __restrict__ sc, const float* __restrict__ tc,
    u16* __restrict__ outb, int N) {
  __shared__ uint4 Ash[64][16];   // hi plane, 16B-block swizzle: pos = q^(row&15)
  __shared__ uint4 Asl[64][16];   // lo (residual) plane
  const int wv = threadIdx.x >> 6;
  const int lane = threadIdx.x & 63;
  const int qt = lane >> 4;       // edge slot within quad
  const int q = lane & 15;        // uint4 slot = features 8q..8q+7
  const int base = blockIdx.x * 64;
  const uint4* __restrict__ H = (const uint4*)hb;

  // ---- phase 1: aggregate 16 rows per wave ----
  for (int t = 0; t < 16; ++t) {
    int row = wv * 16 + t;
    int node = base + row;               // wave-uniform
    if (node >= N) break;
    int beg = offs[node], end = offs[node + 1];

    float2 z2 = make_float2(0.f, 0.f);
    float2 aA0 = z2, aA1 = z2, aA2 = z2, aA3 = z2;
    float2 aB0 = z2, aB1 = z2, aB2 = z2, aB3 = z2;
    {
      uint4 su = H[(size_t)node * 16 + q];
      if (qt == 0) { dacc(aA0, su.x); dacc(aA1, su.y); dacc(aA2, su.z); dacc(aA3, su.w); }
    }
    int i = beg;
    for (; i + 8 <= end; i += 8) {
      int4 sA = *(const int4*)(csr + i);
      int4 sB = *(const int4*)(csr + i + 4);
      int ea = (qt == 0) ? sA.x : (qt == 1) ? sA.y : (qt == 2) ? sA.z : sA.w;
      int eb = (qt == 0) ? sB.x : (qt == 1) ? sB.y : (qt == 2) ? sB.z : sB.w;
      uint4 uA = H[(size_t)ea * 16 + q];
      uint4 uB = H[(size_t)eb * 16 + q];
      dacc(aA0, uA.x); dacc(aA1, uA.y); dacc(aA2, uA.z); dacc(aA3, uA.w);
      dacc(aB0, uB.x); dacc(aB1, uB.y); dacc(aB2, uB.z); dacc(aB3, uB.w);
    }
    if (i < end) {
      int4 sA = *(const int4*)(csr + i);
      int ea = (qt == 0) ? sA.x : (qt == 1) ? sA.y : (qt == 2) ? sA.z : sA.w;
      uint4 uA = H[(size_t)ea * 16 + q];
      dacc(aA0, uA.x); dacc(aA1, uA.y); dacc(aA2, uA.z); dacc(aA3, uA.w);
    }
    float r[8];
    r[0] = aA0.x + aB0.x; r[1] = aA0.y + aB0.y;
    r[2] = aA1.x + aB1.x; r[3] = aA1.y + aB1.y;
    r[4] = aA2.x + aB2.x; r[5] = aA2.y + aB2.y;
    r[6] = aA3.x + aB3.x; r[7] = aA3.y + aB3.y;
#pragma unroll
    for (int j = 0; j < 8; ++j) {
      r[j] += __shfl_xor(r[j], 16, 64);
      r[j] += __shfl_xor(r[j], 32, 64);
    }
    if (qt == 0) {
      float dn = dis[node];
      u32 hw[8];
      uint4 ph, pl;
#pragma unroll
      for (int j = 0; j < 8; ++j) { r[j] *= dn; hw[j] = f2bf(r[j]); }
      ph.x = hw[0] | (hw[1] << 16);
      ph.y = hw[2] | (hw[3] << 16);
      ph.z = hw[4] | (hw[5] << 16);
      ph.w = hw[6] | (hw[7] << 16);
      float l[8];
#pragma unroll
      for (int j = 0; j < 8; ++j) l[j] = r[j] - __uint_as_float(hw[j] << 16);
      pl.x = pack2bf(l[0], l[1]);
      pl.y = pack2bf(l[2], l[3]);
      pl.z = pack2bf(l[4], l[5]);
      pl.w = pack2bf(l[6], l[7]);
      int sw = q ^ (row & 15);
      Ash[row][sw] = ph;
      Asl[row][sw] = pl;
    }
  }
  __syncthreads();

  // ---- phase 2: wave wv GEMMs rows [base+wv*16, +16) ----
  const int lr = lane & 15;
  const int kg = lane >> 4;
  const int rowbase = wv * 16;
  const int arow = rowbase + lr;
  bf16x8 ah[4], al[4];
#pragma unroll
  for (int ks = 0; ks < 4; ++ks) {
    int b = (kg + 4 * ks) ^ (arow & 15);
    ah[ks] = *(const bf16x8*)&Ash[arow][b];
    al[ks] = *(const bf16x8*)&Asl[arow][b];
  }
  float dr[4];
  if (MODE == 0) {
#pragma unroll
    for (int j = 0; j < 4; ++j)
      dr[j] = dis[min(base + rowbase + kg * 4 + j, N - 1)];
  }
#pragma unroll
  for (int ct = 0; ct < 8; ++ct) {
    int c = ct * 16 + lr;
    const bf16x8* pBh = (const bf16x8*)(Wht + (size_t)c * 128 + kg * 8);
    const bf16x8* pBl = (const bf16x8*)(Wlt + (size_t)c * 128 + kg * 8);
    bf16x8 bh[4], bl[4];
#pragma unroll
    for (int ks = 0; ks < 4; ++ks) { bh[ks] = pBh[ks * 4]; bl[ks] = pBl[ks * 4]; }
    float s = sc[c], t = tc[c];
    f32x4 acc = {0.f, 0.f, 0.f, 0.f};
#pragma unroll
    for (int ks = 0; ks < 4; ++ks) {
      acc = __builtin_amdgcn_mfma_f32_16x16x32_bf16(ah[ks], bh[ks], acc, 0, 0, 0);
      acc = __builtin_amdgcn_mfma_f32_16x16x32_bf16(al[ks], bh[ks], acc, 0, 0, 0);
      acc = __builtin_amdgcn_mfma_f32_16x16x32_bf16(ah[ks], bl[ks], acc, 0, 0, 0);
    }
    // C/D: col = lane&15, row = (lane>>4)*4 + j   [m89-verified]
#pragma unroll
    for (int j = 0; j < 4; ++j) {
      int row = base + rowbase + kg * 4 + j;
      if (row < N) {
        float o = fmaxf(fmaf(acc[j], s, t), 0.f);
        if (MODE == 0) o *= dr[j];
        outb[(size_t)row * 128 + c] = (u16)f2bf(o);
      }
    }
  }
}

// ---------------- pooling (bf16 input) + classifier ----------------
__global__ __launch_bounds__(128) void k_pool(
    const u16* __restrict__ hb, const int* __restrict__ batch,
    float* __restrict__ pooled, int N) {
  int f = threadIdx.x;
  int n0 = blockIdx.x * 128;
  int nEnd = min(n0 + 128, N);
  float acc = 0.f;
  int cur = -1;
  for (int nn = n0; nn < nEnd; ++nn) {
    int g = batch[nn];
    if (g != cur) {
      if (cur >= 0) atomicAdd(&pooled[cur * 128 + f], acc);
      cur = g;
      acc = 0.f;
    }
    acc += __uint_as_float((u32)hb[(size_t)nn * 128 + f] << 16);
  }
  if (cur >= 0) atomicAdd(&pooled[cur * 128 + f], acc);
}

__global__ __launch_bounds__(64) void k_cls(
    const float* __restrict__ pooled, const int* __restrict__ batch, int N,
    const float* __restrict__ Wc1, const float* __restrict__ bc1,
    const float* __restrict__ Wc2, const float* __restrict__ bc2,
    float* __restrict__ out, int G) {
  __shared__ float pm[128];
  __shared__ float hid[64];
  __shared__ float invc_s;
  int g = blockIdx.x, t = threadIdx.x;
  if (t == 0) {
    int lo = 0, hi = N;
    while (lo < hi) { int m = (lo + hi) >> 1; if (batch[m] < g) lo = m + 1; else hi = m; }
    int lb = lo;
    lo = 0; hi = N;
    while (lo < hi) { int m = (lo + hi) >> 1; if (batch[m] <= g) lo = m + 1; else hi = m; }
    invc_s = 1.f / fmaxf((float)(lo - lb), 1.f);
  }
  __syncthreads();
  float invc = invc_s;
  pm[t]      = pooled[g * 128 + t] * invc;
  pm[t + 64] = pooled[g * 128 + 64 + t] * invc;
  __syncthreads();
  float a = bc1[t];
#pragma unroll 8
  for (int k = 0; k < 128; ++k) a = fmaf(pm[k], Wc1[k * 64 + t], a);
  hid[t] = fmaxf(a, 0.f);
  __syncthreads();
  if (t < 10) {
    float a2 = bc2[t];
#pragma unroll
    for (int j = 0; j < 64; ++j) a2 = fmaf(hid[j], Wc2[j * 10 + t], a2);
    out[g * 10 + t] = a2;
  }
}

extern "C" void kernel_launch(void* const* d_in, const int* in_sizes, int n_in,
                              void* d_out, int out_size, void* d_ws, size_t ws_size,
                              hipStream_t stream) {
  const float* x   = (const float*)d_in[0];
  const int*   ei  = (const int*)d_in[1];
  const int* batch = (const int*)d_in[2];
  const float* W1 = (const float*)d_in[3];
  const float* b1 = (const float*)d_in[4];
  const float* g1 = (const float*)d_in[5];
  const float* be1 = (const float*)d_in[6];
  const float* m1 = (const float*)d_in[7];
  const float* v1 = (const float*)d_in[8];
  const float* W2 = (const float*)d_in[9];
  const float* b2 = (const float*)d_in[10];
  const float* g2 = (const float*)d_in[11];
  const float* be2 = (const float*)d_in[12];
  const float* m2 = (const float*)d_in[13];
  const float* v2 = (const float*)d_in[14];
  const float* W3 = (const float*)d_in[15];
  const float* b3 = (const float*)d_in[16];
  const float* g3 = (const float*)d_in[17];
  const float* be3 = (const float*)d_in[18];
  const float* m3 = (const float*)d_in[19];
  const float* v3 = (const float*)d_in[20];
  const float* Wc1 = (const float*)d_in[21];
  const float* bc1 = (const float*)d_in[22];
  const float* Wc2 = (const float*)d_in[23];
  const float* bc2 = (const float*)d_in[24];

  const int N = in_sizes[0] / 13;
  const int E = in_sizes[1] / 2;
  const int G = out_size / 10;
  const int* src = ei;
  const int* dst = ei + E;

  char* ws = (char*)d_ws;
  size_t off = 0;
  auto alloc = [&](size_t bytes) {
    char* p = ws + off;
    off = (off + bytes + 255) & ~(size_t)255;
    return p;
  };
  int*   deg    = (int*)  alloc((size_t)N * 4);
  float* dis    = (float*)alloc((size_t)N * 4);
  int*   pdeg   = (int*)  alloc((size_t)N * 4);
  int*   offs   = (int*)  alloc((size_t)(N + 1) * 4);
  const int nb  = (N + 255) / 256;
  int*   bsum   = (int*)  alloc((size_t)nb * 4);
  int*   bexc   = (int*)  alloc((size_t)nb * 4);
  int*   rank   = (int*)  alloc((size_t)E * 4);
  int*   csr    = (int*)  alloc(((size_t)E + 3 * (size_t)N + 8) * 4);
  u16*   hbf    = (u16*)  alloc((size_t)(N + 1) * 128 * 2);   // hs1 bf16 / later h3 bf16
  u16*   hbf2   = (u16*)  alloc((size_t)(N + 1) * 128 * 2);   // hs2 bf16 (layer-2 out)
  float* xs     = (float*)alloc((size_t)(N + 1) * 16 * 4);    // scaled padded x
  float* ax     = (float*)alloc((size_t)N * 16 * 4);          // layer-1 aggregated x
  u16*   Wht2   = (u16*)  alloc(16384 * 2);
  u16*   Wlt2   = (u16*)  alloc(16384 * 2);
  u16*   Wht3   = (u16*)  alloc(16384 * 2);
  u16*   Wlt3   = (u16*)  alloc(16384 * 2);
  float* sc2    = (float*)alloc(128 * 4);
  float* tc2    = (float*)alloc(128 * 4);
  float* sc3    = (float*)alloc(128 * 4);
  float* tc3    = (float*)alloc(128 * 4);
  float* pooled = (float*)alloc((size_t)G * 128 * 4);

  // prep_w also zeroes deg, pooled, and hbf2's pad row (row N)
  k_prep_w<<<128, 256, 0, stream>>>(W2, W3, b2, g2, be2, m2, v2, b3, g3, be3, m3, v3,
                                    Wht2, Wlt2, Wht3, Wlt3, sc2, tc2, sc3, tc3,
                                    deg, pooled, (u32*)(hbf2 + (size_t)N * 128),
                                    N, G * 128);

  const int nE8 = (E + 7) / 8;
  k_hist_rank<<<(nE8 + 255) / 256, 256, 0, stream>>>(dst, deg, rank, E);
  k_prep_nodes<<<(N + 256) / 256, 256, 0, stream>>>(deg, x, dis, pdeg, xs, N);
  k_scan_block<<<nb, 256, 0, stream>>>(pdeg, offs, bsum, N);
  k_scan_bsum<<<1, 512, 0, stream>>>(bsum, bexc, nb);
  k_add_back_pad<<<nb, 256, 0, stream>>>(offs, bexc, bsum, deg, pdeg, csr, N, nb);
  const int nE4 = (E + 3) / 4;
  k_fill_rank<<<(nE4 + 255) / 256, 256, 0, stream>>>(src, dst, rank, offs, csr, E);

  k_agg16<<<(N + 3) / 4, 64, 0, stream>>>(xs, csr, offs, dis, ax, N);
  k_gemm1<<<1024, 256, 0, stream>>>(ax, W1, b1, g1, be1, m1, v1, dis, (u32*)hbf, N);

  const int fusedGrid = (N + 63) / 64;
  k_agg_gemm<0><<<fusedGrid, 256, 0, stream>>>(hbf, csr, offs, dis,
                                               Wht2, Wlt2, sc2, tc2, hbf2, N);
  k_agg_gemm<1><<<fusedGrid, 256, 0, stream>>>(hbf2, csr, offs, dis,
                                               Wht3, Wlt3, sc3, tc3, hbf, N);

  k_pool<<<(N + 127) / 128, 128, 0, stream>>>(hbf, batch, pooled, N);
  k_cls<<<G, 64, 0, stream>>>(pooled, batch, N, Wc1, bc1, Wc2, bc2, (float*)d_out, G);
}

// Round 12
// 630.735 us; speedup vs baseline: 1.0184x; 1.0184x over previous
//
#include <hip/hip_runtime.h>
#include <hip/hip_bf16.h>

#define EPS 1e-5f

typedef unsigned short u16;
typedef unsigned int u32;
typedef __attribute__((ext_vector_type(8))) short bf16x8;
typedef __attribute__((ext_vector_type(4))) float f32x4;

// ---- bf16 helpers (RNE encode, shift decode) ----
__device__ __forceinline__ u32 f2bf(float f) {
  u32 u = __float_as_uint(f);
  return (u + 0x7FFFu + ((u >> 16) & 1u)) >> 16;
}
__device__ __forceinline__ u32 pack2bf(float lo, float hi) {
  return f2bf(lo) | (f2bf(hi) << 16);
}

// accumulate 2 packed bf16 into float2 accumulator
__device__ __forceinline__ void dacc(float2& a, u32 u) {
  a.x += __uint_as_float(u << 16);
  a.y += __uint_as_float(u & 0xFFFF0000u);
}

// ---------------- CSR build: histogram + per-edge rank (8 edges/thread) ----------------
// NOTE: at the device-scope atomic-transaction wall (~24 G/s, 56 MB memory-side
// traffic) — measured invariant under ILP depth 4->8 (R8/R10). Do not touch.
__global__ void k_hist_rank(const int* __restrict__ dst, int* __restrict__ cnt,
                            int* __restrict__ rank, int E) {
  int i = blockIdx.x * blockDim.x + threadIdx.x;
  int i8 = i << 3;
  if (i8 + 7 < E) {
    int4 da = *(const int4*)(dst + i8);
    int4 db = *(const int4*)(dst + i8 + 4);
    int r0 = atomicAdd(&cnt[da.x], 1);
    int r1 = atomicAdd(&cnt[da.y], 1);
    int r2 = atomicAdd(&cnt[da.z], 1);
    int r3 = atomicAdd(&cnt[da.w], 1);
    int r4 = atomicAdd(&cnt[db.x], 1);
    int r5 = atomicAdd(&cnt[db.y], 1);
    int r6 = atomicAdd(&cnt[db.z], 1);
    int r7 = atomicAdd(&cnt[db.w], 1);
    *(int4*)(rank + i8)     = make_int4(r0, r1, r2, r3);
    *(int4*)(rank + i8 + 4) = make_int4(r4, r5, r6, r7);
  } else {
    for (int e = i8; e < E; ++e) rank[e] = atomicAdd(&cnt[dst[e]], 1);
  }
}

// fused: dis, pdeg, and xs = dis * x (padded 13->16, row N zeroed)
__global__ void k_prep_nodes(const int* __restrict__ cnt, const float* __restrict__ x,
                             float* __restrict__ dis, int* __restrict__ pdeg,
                             float* __restrict__ xs, int N) {
  int n = blockIdx.x * blockDim.x + threadIdx.x;
  if (n > N) return;
  if (n == N) {
#pragma unroll
    for (int f = 0; f < 16; f += 4)
      *(float4*)(xs + (size_t)N * 16 + f) = make_float4(0.f, 0.f, 0.f, 0.f);
    return;
  }
  int d = cnt[n];
  float dn = rsqrtf((float)d + 1.0f);
  dis[n] = dn;
  pdeg[n] = (d + 3) & ~3;
  float v[16];
#pragma unroll
  for (int f = 0; f < 13; ++f) v[f] = x[(size_t)n * 13 + f] * dn;
  v[13] = v[14] = v[15] = 0.f;
#pragma unroll
  for (int f = 0; f < 16; f += 4)
    *(float4*)(xs + (size_t)n * 16 + f) = make_float4(v[f], v[f+1], v[f+2], v[f+3]);
}

__global__ void k_scan_block(const int* __restrict__ in, int* __restrict__ out,
                             int* __restrict__ bsum, int N) {
  __shared__ int tmp[256];
  int lid = threadIdx.x;
  int i = blockIdx.x * 256 + lid;
  int v = (i < N) ? in[i] : 0;
  tmp[lid] = v;
  __syncthreads();
  for (int off = 1; off < 256; off <<= 1) {
    int t = (lid >= off) ? tmp[lid - off] : 0;
    __syncthreads();
    tmp[lid] += t;
    __syncthreads();
  }
  if (i < N) out[i] = tmp[lid] - v;            // exclusive within block
  if (lid == 255) bsum[blockIdx.x] = tmp[255];
}

__global__ void k_scan_bsum(const int* __restrict__ bsum, int* __restrict__ bexc, int nb) {
  __shared__ int tmp[512];
  int lid = threadIdx.x;
  int v = (lid < nb) ? bsum[lid] : 0;
  tmp[lid] = v;
  __syncthreads();
  for (int off = 1; off < 512; off <<= 1) {
    int t = (lid >= off) ? tmp[lid - off] : 0;
    __syncthreads();
    tmp[lid] += t;
    __syncthreads();
  }
  if (lid < nb) bexc[lid] = tmp[lid] - v;      // exclusive
}

// fused: finalize offs + fill dummy pad slots (disjoint from real slots, order-free)
__global__ void k_add_back_pad(int* __restrict__ offs, const int* __restrict__ bexc,
                               const int* __restrict__ bsum, const int* __restrict__ deg,
                               const int* __restrict__ pdeg, int* __restrict__ csr,
                               int N, int nb) {
  int i = blockIdx.x * 256 + threadIdx.x;
  if (i < N) {
    int o = offs[i] + bexc[blockIdx.x];
    offs[i] = o;
    int b = o + deg[i], e = o + pdeg[i];
    for (int j = b; j < e; ++j) csr[j] = N;
  }
  if (i == 0) offs[N] = bexc[nb - 1] + bsum[nb - 1];   // total padded count
}

// slot = offs[dst] + rank  (no atomic; scatter store is fire-and-forget)
__global__ void k_fill_rank(const int* __restrict__ src, const int* __restrict__ dst,
                            const int* __restrict__ rank, const int* __restrict__ offs,
                            int* __restrict__ csr, int E) {
  int i = blockIdx.x * blockDim.x + threadIdx.x;
  int i4 = i << 2;
  if (i4 + 3 < E) {
    int s0 = src[i4], s1 = src[i4 + 1], s2 = src[i4 + 2], s3 = src[i4 + 3];
    int d0 = dst[i4], d1 = dst[i4 + 1], d2 = dst[i4 + 2], d3 = dst[i4 + 3];
    int r0 = rank[i4], r1 = rank[i4 + 1], r2 = rank[i4 + 2], r3 = rank[i4 + 3];
    csr[offs[d0] + r0] = s0;
    csr[offs[d1] + r1] = s1;
    csr[offs[d2] + r2] = s2;
    csr[offs[d3] + r3] = s3;
  } else {
    for (int e = i4; e < E; ++e) csr[offs[dst[e]] + rank[e]] = src[e];
  }
}

// ---------------- W prep: split-transpose to bf16 hi/lo + BN scale fold ----------------
// Also zeroes deg, pooled, and the pad row of hbf2 (replaces hipMemsetAsync).
__global__ void k_prep_w(const float* __restrict__ W2, const float* __restrict__ W3,
                         const float* __restrict__ b2, const float* __restrict__ g2,
                         const float* __restrict__ be2, const float* __restrict__ m2,
                         const float* __restrict__ v2,
                         const float* __restrict__ b3, const float* __restrict__ g3,
                         const float* __restrict__ be3, const float* __restrict__ m3,
                         const float* __restrict__ v3,
                         u16* __restrict__ Wht2, u16* __restrict__ Wlt2,
                         u16* __restrict__ Wht3, u16* __restrict__ Wlt3,
                         float* __restrict__ sc2, float* __restrict__ tc2,
                         float* __restrict__ sc3, float* __restrict__ tc3,
                         int* __restrict__ deg, float* __restrict__ pooled,
                         u32* __restrict__ hbf2_padrow, int N, int GP) {
  int idx = blockIdx.x * 256 + threadIdx.x;     // 0..32767
  int layer = idx >> 14;
  int e = idx & 16383;
  int c = e >> 7, k = e & 127;
  const float* W = layer ? W3 : W2;
  float w = W[k * 128 + c];                     // transpose read
  u32 h = f2bf(w);
  float l = w - __uint_as_float(h << 16);
  u16* Wh = layer ? Wht3 : Wht2;
  u16* Wl = layer ? Wlt3 : Wlt2;
  Wh[e] = (u16)h;                               // [c][k] layout
  Wl[e] = (u16)f2bf(l);
  if (e < 128) {
    int ch = e;
    const float* gg = layer ? g3 : g2;  const float* vv = layer ? v3 : v2;
    const float* be = layer ? be3 : be2; const float* mm = layer ? m3 : m2;
    const float* bb = layer ? b3 : b2;
    float s = gg[ch] * rsqrtf(vv[ch] + EPS);
    (layer ? sc3 : sc2)[ch] = s;
    (layer ? tc3 : tc2)[ch] = be[ch] + (bb[ch] - mm[ch]) * s;
  }
  for (int i = idx; i < N; i += 32768) deg[i] = 0;
  for (int i = idx; i < GP; i += 32768) pooled[i] = 0.f;
  if (idx < 64) hbf2_padrow[idx] = 0u;          // zero pad row (128 bf16)
}

// agg[d] = dis[d] * (sum_{s in padded N(d)} xs[s] + xs[d]); exact 4-edge steps
__global__ __launch_bounds__(64) void k_agg16(
    const float* __restrict__ xs, const int* __restrict__ csr,
    const int* __restrict__ offs, const float* __restrict__ dis,
    float* __restrict__ out, int N) {
  int node = (blockIdx.x << 2) + (threadIdx.x >> 4);
  if (node >= N) return;
  int f = threadIdx.x & 15;
  float a0 = xs[(size_t)node * 16 + f];   // self, weight 1
  float a1 = 0.f, a2 = 0.f, a3 = 0.f;
  int beg = offs[node], end = offs[node + 1];
  for (int i = beg; i < end; i += 4) {
    int4 s4 = *(const int4*)(csr + i);
    a0 += xs[(size_t)s4.x * 16 + f];
    a1 += xs[(size_t)s4.y * 16 + f];
    a2 += xs[(size_t)s4.z * 16 + f];
    a3 += xs[(size_t)s4.w * 16 + f];
  }
  out[(size_t)node * 16 + f] = dis[node] * ((a0 + a1) + (a2 + a3));
}

// K=13 GEMM + BN/ReLU, hs1 = dis*h1 bf16. Wave owns 128 channels (2/lane).
__global__ __launch_bounds__(256) void k_gemm1(
    const float* __restrict__ ax, const float* __restrict__ W1,
    const float* __restrict__ bb, const float* __restrict__ gg,
    const float* __restrict__ be, const float* __restrict__ mm,
    const float* __restrict__ vv, const float* __restrict__ dis,
    u32* __restrict__ outb, int N) {
  const int lane = threadIdx.x & 63;
  const int wid = blockIdx.x * (blockDim.x >> 6) + (threadIdx.x >> 6);
  const int nw = gridDim.x * (blockDim.x >> 6);
  const int c0 = lane * 2, c1 = c0 + 1;
  float s0 = gg[c0] * rsqrtf(vv[c0] + EPS);
  float t0 = be[c0] + (bb[c0] - mm[c0]) * s0;
  float s1 = gg[c1] * rsqrtf(vv[c1] + EPS);
  float t1 = be[c1] + (bb[c1] - mm[c1]) * s1;
  float w0[13], w1[13];
#pragma unroll
  for (int k = 0; k < 13; ++k) {
    w0[k] = W1[k * 128 + c0];
    w1[k] = W1[k * 128 + c1];
  }
  for (int node = wid; node <= N; node += nw) {
    if (node == N) { outb[(size_t)node * 64 + lane] = 0u; continue; }
    float4 A0 = *(const float4*)(ax + (size_t)node * 16);
    float4 A1 = *(const float4*)(ax + (size_t)node * 16 + 4);
    float4 A2 = *(const float4*)(ax + (size_t)node * 16 + 8);
    float  a12 = ax[(size_t)node * 16 + 12];
    float av[13] = {A0.x, A0.y, A0.z, A0.w, A1.x, A1.y, A1.z, A1.w,
                    A2.x, A2.y, A2.z, A2.w, a12};
    float acc0 = 0.f, acc1 = 0.f;
#pragma unroll
    for (int k = 0; k < 13; ++k) {
      acc0 = fmaf(av[k], w0[k], acc0);
      acc1 = fmaf(av[k], w1[k], acc1);
    }
    float dn = dis[node];
    float o0 = dn * fmaxf(fmaf(acc0, s0, t0), 0.f);
    float o1 = dn * fmaxf(fmaf(acc1, s1, t1), 0.f);
    outb[(size_t)node * 64 + lane] = pack2bf(o0, o1);
  }
}

// ---- FUSED v2: aggregation -> LDS -> bf16x3 MFMA GEMM; 2 waves, 32 rows, 16KB LDS ----
// Phase 1: wave wv aggregates rows [wv*16, wv*16+16) into XOR-swizzled LDS.
// Phase 2: wave wv GEMMs its 16 rows. 16KB LDS -> ~10 blocks/CU, occupancy restored
// (R11's 4-wave/32KB variant choked at 32% occupancy / 1.23 TB/s gather).
// IN and OUT must differ (other blocks still gather from IN).
// MODE 0: out = bf16(dis*relu(...));  MODE 1: out = bf16(relu(...)).
template <int MODE>
__global__ __launch_bounds__(128) void k_agg_gemm(
    const u16* __restrict__ hb, const int* __restrict__ csr,
    const int* __restrict__ offs, const float* __restrict__ dis,
    const u16* __restrict__ Wht, const u16* __restrict__ Wlt,
    const float* __restrict__ sc, const float* __restrict__ tc,
    u16* __restrict__ outb, int N) {
  __shared__ uint4 Ash[32][16];   // hi plane, 16B-block swizzle: pos = q^(row&15)
  __shared__ uint4 Asl[32][16];   // lo (residual) plane
  const int wv = threadIdx.x >> 6;        // 0..1
  const int lane = threadIdx.x & 63;
  const int qt = lane >> 4;       // edge slot within quad
  const int q = lane & 15;        // uint4 slot = features 8q..8q+7
  const int base = blockIdx.x * 32;
  const uint4* __restrict__ H = (const uint4*)hb;

  // ---- phase 1: aggregate 16 rows per wave ----
  for (int t = 0; t < 16; ++t) {
    int row = wv * 16 + t;
    int node = base + row;               // wave-uniform
    if (node >= N) break;
    int beg = offs[node], end = offs[node + 1];

    float2 z2 = make_float2(0.f, 0.f);
    float2 aA0 = z2, aA1 = z2, aA2 = z2, aA3 = z2;
    float2 aB0 = z2, aB1 = z2, aB2 = z2, aB3 = z2;
    {
      uint4 su = H[(size_t)node * 16 + q];
      if (qt == 0) { dacc(aA0, su.x); dacc(aA1, su.y); dacc(aA2, su.z); dacc(aA3, su.w); }
    }
    int i = beg;
    for (; i + 8 <= end; i += 8) {
      int4 sA = *(const int4*)(csr + i);
      int4 sB = *(const int4*)(csr + i + 4);
      int ea = (qt == 0) ? sA.x : (qt == 1) ? sA.y : (qt == 2) ? sA.z : sA.w;
      int eb = (qt == 0) ? sB.x : (qt == 1) ? sB.y : (qt == 2) ? sB.z : sB.w;
      uint4 uA = H[(size_t)ea * 16 + q];
      uint4 uB = H[(size_t)eb * 16 + q];
      dacc(aA0, uA.x); dacc(aA1, uA.y); dacc(aA2, uA.z); dacc(aA3, uA.w);
      dacc(aB0, uB.x); dacc(aB1, uB.y); dacc(aB2, uB.z); dacc(aB3, uB.w);
    }
    if (i < end) {
      int4 sA = *(const int4*)(csr + i);
      int ea = (qt == 0) ? sA.x : (qt == 1) ? sA.y : (qt == 2) ? sA.z : sA.w;
      uint4 uA = H[(size_t)ea * 16 + q];
      dacc(aA0, uA.x); dacc(aA1, uA.y); dacc(aA2, uA.z); dacc(aA3, uA.w);
    }
    float r[8];
    r[0] = aA0.x + aB0.x; r[1] = aA0.y + aB0.y;
    r[2] = aA1.x + aB1.x; r[3] = aA1.y + aB1.y;
    r[4] = aA2.x + aB2.x; r[5] = aA2.y + aB2.y;
    r[6] = aA3.x + aB3.x; r[7] = aA3.y + aB3.y;
#pragma unroll
    for (int j = 0; j < 8; ++j) {
      r[j] += __shfl_xor(r[j], 16, 64);
      r[j] += __shfl_xor(r[j], 32, 64);
    }
    if (qt == 0) {
      float dn = dis[node];
      u32 hw[8];
      uint4 ph, pl;
#pragma unroll
      for (int j = 0; j < 8; ++j) { r[j] *= dn; hw[j] = f2bf(r[j]); }
      ph.x = hw[0] | (hw[1] << 16);
      ph.y = hw[2] | (hw[3] << 16);
      ph.z = hw[4] | (hw[5] << 16);
      ph.w = hw[6] | (hw[7] << 16);
      float l[8];
#pragma unroll
      for (int j = 0; j < 8; ++j) l[j] = r[j] - __uint_as_float(hw[j] << 16);
      pl.x = pack2bf(l[0], l[1]);
      pl.y = pack2bf(l[2], l[3]);
      pl.z = pack2bf(l[4], l[5]);
      pl.w = pack2bf(l[6], l[7]);
      int sw = q ^ (row & 15);
      Ash[row][sw] = ph;
      Asl[row][sw] = pl;
    }
  }
  __syncthreads();

  // ---- phase 2: wave wv GEMMs rows [base+wv*16, +16) ----
  const int lr = lane & 15;
  const int kg = lane >> 4;
  const int rowbase = wv * 16;
  const int arow = rowbase + lr;
  bf16x8 ah[4], al[4];
#pragma unroll
  for (int ks = 0; ks < 4; ++ks) {
    int b = (kg + 4 * ks) ^ (arow & 15);
    ah[ks] = *(const bf16x8*)&Ash[arow][b];
    al[ks] = *(const bf16x8*)&Asl[arow][b];
  }
  float dr[4];
  if (MODE == 0) {
#pragma unroll
    for (int j = 0; j < 4; ++j)
      dr[j] = dis[min(base + rowbase + kg * 4 + j, N - 1)];
  }
#pragma unroll
  for (int ct = 0; ct < 8; ++ct) {
    int c = ct * 16 + lr;
    const bf16x8* pBh = (const bf16x8*)(Wht + (size_t)c * 128 + kg * 8);
    const bf16x8* pBl = (const bf16x8*)(Wlt + (size_t)c * 128 + kg * 8);
    bf16x8 bh[4], bl[4];
#pragma unroll
    for (int ks = 0; ks < 4; ++ks) { bh[ks] = pBh[ks * 4]; bl[ks] = pBl[ks * 4]; }
    float s = sc[c], t = tc[c];
    f32x4 acc = {0.f, 0.f, 0.f, 0.f};
#pragma unroll
    for (int ks = 0; ks < 4; ++ks) {
      acc = __builtin_amdgcn_mfma_f32_16x16x32_bf16(ah[ks], bh[ks], acc, 0, 0, 0);
      acc = __builtin_amdgcn_mfma_f32_16x16x32_bf16(al[ks], bh[ks], acc, 0, 0, 0);
      acc = __builtin_amdgcn_mfma_f32_16x16x32_bf16(ah[ks], bl[ks], acc, 0, 0, 0);
    }
    // C/D: col = lane&15, row = (lane>>4)*4 + j   [m89-verified]
#pragma unroll
    for (int j = 0; j < 4; ++j) {
      int row = base + rowbase + kg * 4 + j;
      if (row < N) {
        float o = fmaxf(fmaf(acc[j], s, t), 0.f);
        if (MODE == 0) o *= dr[j];
        outb[(size_t)row * 128 + c] = (u16)f2bf(o);
      }
    }
  }
}

// ---------------- pooling (bf16 input) + classifier ----------------
__global__ __launch_bounds__(128) void k_pool(
    const u16* __restrict__ hb, const int* __restrict__ batch,
    float* __restrict__ pooled, int N) {
  int f = threadIdx.x;
  int n0 = blockIdx.x * 128;
  int nEnd = min(n0 + 128, N);
  float acc = 0.f;
  int cur = -1;
  for (int nn = n0; nn < nEnd; ++nn) {
    int g = batch[nn];
    if (g != cur) {
      if (cur >= 0) atomicAdd(&pooled[cur * 128 + f], acc);
      cur = g;
      acc = 0.f;
    }
    acc += __uint_as_float((u32)hb[(size_t)nn * 128 + f] << 16);
  }
  if (cur >= 0) atomicAdd(&pooled[cur * 128 + f], acc);
}

__global__ __launch_bounds__(64) void k_cls(
    const float* __restrict__ pooled, const int* __restrict__ batch, int N,
    const float* __restrict__ Wc1, const float* __restrict__ bc1,
    const float* __restrict__ Wc2, const float* __restrict__ bc2,
    float* __restrict__ out, int G) {
  __shared__ float pm[128];
  __shared__ float hid[64];
  __shared__ float invc_s;
  int g = blockIdx.x, t = threadIdx.x;
  if (t == 0) {
    int lo = 0, hi = N;
    while (lo < hi) { int m = (lo + hi) >> 1; if (batch[m] < g) lo = m + 1; else hi = m; }
    int lb = lo;
    lo = 0; hi = N;
    while (lo < hi) { int m = (lo + hi) >> 1; if (batch[m] <= g) lo = m + 1; else hi = m; }
    invc_s = 1.f / fmaxf((float)(lo - lb), 1.f);
  }
  __syncthreads();
  float invc = invc_s;
  pm[t]      = pooled[g * 128 + t] * invc;
  pm[t + 64] = pooled[g * 128 + 64 + t] * invc;
  __syncthreads();
  float a = bc1[t];
#pragma unroll 8
  for (int k = 0; k < 128; ++k) a = fmaf(pm[k], Wc1[k * 64 + t], a);
  hid[t] = fmaxf(a, 0.f);
  __syncthreads();
  if (t < 10) {
    float a2 = bc2[t];
#pragma unroll
    for (int j = 0; j < 64; ++j) a2 = fmaf(hid[j], Wc2[j * 10 + t], a2);
    out[g * 10 + t] = a2;
  }
}

extern "C" void kernel_launch(void* const* d_in, const int* in_sizes, int n_in,
                              void* d_out, int out_size, void* d_ws, size_t ws_size,
                              hipStream_t stream) {
  const float* x   = (const float*)d_in[0];
  const int*   ei  = (const int*)d_in[1];
  const int* batch = (const int*)d_in[2];
  const float* W1 = (const float*)d_in[3];
  const float* b1 = (const float*)d_in[4];
  const float* g1 = (const float*)d_in[5];
  const float* be1 = (const float*)d_in[6];
  const float* m1 = (const float*)d_in[7];
  const float* v1 = (const float*)d_in[8];
  const float* W2 = (const float*)d_in[9];
  const float* b2 = (const float*)d_in[10];
  const float* g2 = (const float*)d_in[11];
  const float* be2 = (const float*)d_in[12];
  const float* m2 = (const float*)d_in[13];
  const float* v2 = (const float*)d_in[14];
  const float* W3 = (const float*)d_in[15];
  const float* b3 = (const float*)d_in[16];
  const float* g3 = (const float*)d_in[17];
  const float* be3 = (const float*)d_in[18];
  const float* m3 = (const float*)d_in[19];
  const float* v3 = (const float*)d_in[20];
  const float* Wc1 = (const float*)d_in[21];
  const float* bc1 = (const float*)d_in[22];
  const float* Wc2 = (const float*)d_in[23];
  const float* bc2 = (const float*)d_in[24];

  const int N = in_sizes[0] / 13;
  const int E = in_sizes[1] / 2;
  const int G = out_size / 10;
  const int* src = ei;
  const int* dst = ei + E;

  char* ws = (char*)d_ws;
  size_t off = 0;
  auto alloc = [&](size_t bytes) {
    char* p = ws + off;
    off = (off + bytes + 255) & ~(size_t)255;
    return p;
  };
  int*   deg    = (int*)  alloc((size_t)N * 4);
  float* dis    = (float*)alloc((size_t)N * 4);
  int*   pdeg   = (int*)  alloc((size_t)N * 4);
  int*   offs   = (int*)  alloc((size_t)(N + 1) * 4);
  const int nb  = (N + 255) / 256;
  int*   bsum   = (int*)  alloc((size_t)nb * 4);
  int*   bexc   = (int*)  alloc((size_t)nb * 4);
  int*   rank   = (int*)  alloc((size_t)E * 4);
  int*   csr    = (int*)  alloc(((size_t)E + 3 * (size_t)N + 8) * 4);
  u16*   hbf    = (u16*)  alloc((size_t)(N + 1) * 128 * 2);   // hs1 bf16 / later h3 bf16
  u16*   hbf2   = (u16*)  alloc((size_t)(N + 1) * 128 * 2);   // hs2 bf16 (layer-2 out)
  float* xs     = (float*)alloc((size_t)(N + 1) * 16 * 4);    // scaled padded x
  float* ax     = (float*)alloc((size_t)N * 16 * 4);          // layer-1 aggregated x
  u16*   Wht2   = (u16*)  alloc(16384 * 2);
  u16*   Wlt2   = (u16*)  alloc(16384 * 2);
  u16*   Wht3   = (u16*)  alloc(16384 * 2);
  u16*   Wlt3   = (u16*)  alloc(16384 * 2);
  float* sc2    = (float*)alloc(128 * 4);
  float* tc2    = (float*)alloc(128 * 4);
  float* sc3    = (float*)alloc(128 * 4);
  float* tc3    = (float*)alloc(128 * 4);
  float* pooled = (float*)alloc((size_t)G * 128 * 4);

  // prep_w also zeroes deg, pooled, and hbf2's pad row (row N)
  k_prep_w<<<128, 256, 0, stream>>>(W2, W3, b2, g2, be2, m2, v2, b3, g3, be3, m3, v3,
                                    Wht2, Wlt2, Wht3, Wlt3, sc2, tc2, sc3, tc3,
                                    deg, pooled, (u32*)(hbf2 + (size_t)N * 128),
                                    N, G * 128);

  const int nE8 = (E + 7) / 8;
  k_hist_rank<<<(nE8 + 255) / 256, 256, 0, stream>>>(dst, deg, rank, E);
  k_prep_nodes<<<(N + 256) / 256, 256, 0, stream>>>(deg, x, dis, pdeg, xs, N);
  k_scan_block<<<nb, 256, 0, stream>>>(pdeg, offs, bsum, N);
  k_scan_bsum<<<1, 512, 0, stream>>>(bsum, bexc, nb);
  k_add_back_pad<<<nb, 256, 0, stream>>>(offs, bexc, bsum, deg, pdeg, csr, N, nb);
  const int nE4 = (E + 3) / 4;
  k_fill_rank<<<(nE4 + 255) / 256, 256, 0, stream>>>(src, dst, rank, offs, csr, E);

  k_agg16<<<(N + 3) / 4, 64, 0, stream>>>(xs, csr, offs, dis, ax, N);
  k_gemm1<<<1024, 256, 0, stream>>>(ax, W1, b1, g1, be1, m1, v1, dis, (u32*)hbf, N);

  const int fusedGrid = (N + 31) / 32;
  k_agg_gemm<0><<<fusedGrid, 128, 0, stream>>>(hbf, csr, offs, dis,
                                               Wht2, Wlt2, sc2, tc2, hbf2, N);
  k_agg_gemm<1><<<fusedGrid, 128, 0, stream>>>(hbf2, csr, offs, dis,
                                               Wht3, Wlt3, sc3, tc3, hbf, N);

  k_pool<<<(N + 127) / 128, 128, 0, stream>>>(hbf, batch, pooled, N);
  k_cls<<<G, 64, 0, stream>>>(pooled, batch, N, Wc1, bc1, Wc2, bc2, (float*)d_out, G);
}

// Round 13
// 526.077 us; speedup vs baseline: 1.2210x; 1.1989x over previous
//
#include <hip/hip_runtime.h>
#include <hip/hip_bf16.h>

#define EPS 1e-5f

typedef unsigned short u16;
typedef unsigned int u32;
typedef __attribute__((ext_vector_type(8))) short bf16x8;
typedef __attribute__((ext_vector_type(4))) float f32x4;

// ---- bf16 helpers (RNE encode, shift decode) ----
__device__ __forceinline__ u32 f2bf(float f) {
  u32 u = __float_as_uint(f);
  return (u + 0x7FFFu + ((u >> 16) & 1u)) >> 16;
}
__device__ __forceinline__ u32 pack2bf(float lo, float hi) {
  return f2bf(lo) | (f2bf(hi) << 16);
}

// accumulate 2 packed bf16 into float2 accumulator
__device__ __forceinline__ void dacc(float2& a, u32 u) {
  a.x += __uint_as_float(u << 16);
  a.y += __uint_as_float(u & 0xFFFF0000u);
}

// ---------------- CSR build: histogram + per-edge rank (8 edges/thread) ----------------
// NOTE: at the device-scope atomic-transaction wall (~24 G/s, 56 MB memory-side
// traffic) — measured invariant under ILP depth 4->8 (R8/R10). Do not touch.
__global__ void k_hist_rank(const int* __restrict__ dst, int* __restrict__ cnt,
                            int* __restrict__ rank, int E) {
  int i = blockIdx.x * blockDim.x + threadIdx.x;
  int i8 = i << 3;
  if (i8 + 7 < E) {
    int4 da = *(const int4*)(dst + i8);
    int4 db = *(const int4*)(dst + i8 + 4);
    int r0 = atomicAdd(&cnt[da.x], 1);
    int r1 = atomicAdd(&cnt[da.y], 1);
    int r2 = atomicAdd(&cnt[da.z], 1);
    int r3 = atomicAdd(&cnt[da.w], 1);
    int r4 = atomicAdd(&cnt[db.x], 1);
    int r5 = atomicAdd(&cnt[db.y], 1);
    int r6 = atomicAdd(&cnt[db.z], 1);
    int r7 = atomicAdd(&cnt[db.w], 1);
    *(int4*)(rank + i8)     = make_int4(r0, r1, r2, r3);
    *(int4*)(rank + i8 + 4) = make_int4(r4, r5, r6, r7);
  } else {
    for (int e = i8; e < E; ++e) rank[e] = atomicAdd(&cnt[dst[e]], 1);
  }
}

// fused: dis, pdeg, and xs = dis * x (padded 13->16, row N zeroed)
__global__ void k_prep_nodes(const int* __restrict__ cnt, const float* __restrict__ x,
                             float* __restrict__ dis, int* __restrict__ pdeg,
                             float* __restrict__ xs, int N) {
  int n = blockIdx.x * blockDim.x + threadIdx.x;
  if (n > N) return;
  if (n == N) {
#pragma unroll
    for (int f = 0; f < 16; f += 4)
      *(float4*)(xs + (size_t)N * 16 + f) = make_float4(0.f, 0.f, 0.f, 0.f);
    return;
  }
  int d = cnt[n];
  float dn = rsqrtf((float)d + 1.0f);
  dis[n] = dn;
  pdeg[n] = (d + 3) & ~3;
  float v[16];
#pragma unroll
  for (int f = 0; f < 13; ++f) v[f] = x[(size_t)n * 13 + f] * dn;
  v[13] = v[14] = v[15] = 0.f;
#pragma unroll
  for (int f = 0; f < 16; f += 4)
    *(float4*)(xs + (size_t)n * 16 + f) = make_float4(v[f], v[f+1], v[f+2], v[f+3]);
}

__global__ void k_scan_block(const int* __restrict__ in, int* __restrict__ out,
                             int* __restrict__ bsum, int N) {
  __shared__ int tmp[256];
  int lid = threadIdx.x;
  int i = blockIdx.x * 256 + lid;
  int v = (i < N) ? in[i] : 0;
  tmp[lid] = v;
  __syncthreads();
  for (int off = 1; off < 256; off <<= 1) {
    int t = (lid >= off) ? tmp[lid - off] : 0;
    __syncthreads();
    tmp[lid] += t;
    __syncthreads();
  }
  if (i < N) out[i] = tmp[lid] - v;            // exclusive within block
  if (lid == 255) bsum[blockIdx.x] = tmp[255];
}

__global__ void k_scan_bsum(const int* __restrict__ bsum, int* __restrict__ bexc, int nb) {
  __shared__ int tmp[512];
  int lid = threadIdx.x;
  int v = (lid < nb) ? bsum[lid] : 0;
  tmp[lid] = v;
  __syncthreads();
  for (int off = 1; off < 512; off <<= 1) {
    int t = (lid >= off) ? tmp[lid - off] : 0;
    __syncthreads();
    tmp[lid] += t;
    __syncthreads();
  }
  if (lid < nb) bexc[lid] = tmp[lid] - v;      // exclusive
}

// fused: finalize offs + fill dummy pad slots (disjoint from real slots, order-free)
__global__ void k_add_back_pad(int* __restrict__ offs, const int* __restrict__ bexc,
                               const int* __restrict__ bsum, const int* __restrict__ deg,
                               const int* __restrict__ pdeg, int* __restrict__ csr,
                               int N, int nb) {
  int i = blockIdx.x * 256 + threadIdx.x;
  if (i < N) {
    int o = offs[i] + bexc[blockIdx.x];
    offs[i] = o;
    int b = o + deg[i], e = o + pdeg[i];
    for (int j = b; j < e; ++j) csr[j] = N;
  }
  if (i == 0) offs[N] = bexc[nb - 1] + bsum[nb - 1];   // total padded count
}

// slot = offs[dst] + rank  (no atomic; scatter store is fire-and-forget)
__global__ void k_fill_rank(const int* __restrict__ src, const int* __restrict__ dst,
                            const int* __restrict__ rank, const int* __restrict__ offs,
                            int* __restrict__ csr, int E) {
  int i = blockIdx.x * blockDim.x + threadIdx.x;
  int i4 = i << 2;
  if (i4 + 3 < E) {
    int s0 = src[i4], s1 = src[i4 + 1], s2 = src[i4 + 2], s3 = src[i4 + 3];
    int d0 = dst[i4], d1 = dst[i4 + 1], d2 = dst[i4 + 2], d3 = dst[i4 + 3];
    int r0 = rank[i4], r1 = rank[i4 + 1], r2 = rank[i4 + 2], r3 = rank[i4 + 3];
    csr[offs[d0] + r0] = s0;
    csr[offs[d1] + r1] = s1;
    csr[offs[d2] + r2] = s2;
    csr[offs[d3] + r3] = s3;
  } else {
    for (int e = i4; e < E; ++e) csr[offs[dst[e]] + rank[e]] = src[e];
  }
}

// ---------------- W prep: split-transpose to bf16 hi/lo + BN scale fold ----------------
// Also zeroes deg, pooled, and the pad row of hbf2 (replaces hipMemsetAsync).
__global__ void k_prep_w(const float* __restrict__ W2, const float* __restrict__ W3,
                         const float* __restrict__ b2, const float* __restrict__ g2,
                         const float* __restrict__ be2, const float* __restrict__ m2,
                         const float* __restrict__ v2,
                         const float* __restrict__ b3, const float* __restrict__ g3,
                         const float* __restrict__ be3, const float* __restrict__ m3,
                         const float* __restrict__ v3,
                         u16* __restrict__ Wht2, u16* __restrict__ Wlt2,
                         u16* __restrict__ Wht3, u16* __restrict__ Wlt3,
                         float* __restrict__ sc2, float* __restrict__ tc2,
                         float* __restrict__ sc3, float* __restrict__ tc3,
                         int* __restrict__ deg, float* __restrict__ pooled,
                         u32* __restrict__ hbf_padrow, int N, int GP) {
  int idx = blockIdx.x * 256 + threadIdx.x;     // 0..32767
  int layer = idx >> 14;
  int e = idx & 16383;
  int c = e >> 7, k = e & 127;
  const float* W = layer ? W3 : W2;
  float w = W[k * 128 + c];                     // transpose read
  u32 h = f2bf(w);
  float l = w - __uint_as_float(h << 16);
  u16* Wh = layer ? Wht3 : Wht2;
  u16* Wl = layer ? Wlt3 : Wlt2;
  Wh[e] = (u16)h;                               // [c][k] layout
  Wl[e] = (u16)f2bf(l);
  if (e < 128) {
    int ch = e;
    const float* gg = layer ? g3 : g2;  const float* vv = layer ? v3 : v2;
    const float* be = layer ? be3 : be2; const float* mm = layer ? m3 : m2;
    const float* bb = layer ? b3 : b2;
    float s = gg[ch] * rsqrtf(vv[ch] + EPS);
    (layer ? sc3 : sc2)[ch] = s;
    (layer ? tc3 : tc2)[ch] = be[ch] + (bb[ch] - mm[ch]) * s;
  }
  for (int i = idx; i < N; i += 32768) deg[i] = 0;
  for (int i = idx; i < GP; i += 32768) pooled[i] = 0.f;
  if (idx < 64) hbf_padrow[idx] = 0u;           // zero pad row (128 bf16)
}

// agg[d] = dis[d] * (sum_{s in padded N(d)} xs[s] + xs[d]); exact 4-edge steps
__global__ __launch_bounds__(64) void k_agg16(
    const float* __restrict__ xs, const int* __restrict__ csr,
    const int* __restrict__ offs, const float* __restrict__ dis,
    float* __restrict__ out, int N) {
  int node = (blockIdx.x << 2) + (threadIdx.x >> 4);
  if (node >= N) return;
  int f = threadIdx.x & 15;
  float a0 = xs[(size_t)node * 16 + f];   // self, weight 1
  float a1 = 0.f, a2 = 0.f, a3 = 0.f;
  int beg = offs[node], end = offs[node + 1];
  for (int i = beg; i < end; i += 4) {
    int4 s4 = *(const int4*)(csr + i);
    a0 += xs[(size_t)s4.x * 16 + f];
    a1 += xs[(size_t)s4.y * 16 + f];
    a2 += xs[(size_t)s4.z * 16 + f];
    a3 += xs[(size_t)s4.w * 16 + f];
  }
  out[(size_t)node * 16 + f] = dis[node] * ((a0 + a1) + (a2 + a3));
}

// K=13 GEMM + BN/ReLU, hs1 = dis*h1 bf16. Wave owns 128 channels (2/lane),
// W1 column + BN scale/shift in registers, grid-stride over nodes.
__global__ __launch_bounds__(256) void k_gemm1(
    const float* __restrict__ ax, const float* __restrict__ W1,
    const float* __restrict__ bb, const float* __restrict__ gg,
    const float* __restrict__ be, const float* __restrict__ mm,
    const float* __restrict__ vv, const float* __restrict__ dis,
    u32* __restrict__ outb, int N) {
  const int lane = threadIdx.x & 63;
  const int wid = blockIdx.x * (blockDim.x >> 6) + (threadIdx.x >> 6);
  const int nw = gridDim.x * (blockDim.x >> 6);
  const int c0 = lane * 2, c1 = c0 + 1;
  float s0 = gg[c0] * rsqrtf(vv[c0] + EPS);
  float t0 = be[c0] + (bb[c0] - mm[c0]) * s0;
  float s1 = gg[c1] * rsqrtf(vv[c1] + EPS);
  float t1 = be[c1] + (bb[c1] - mm[c1]) * s1;
  float w0[13], w1[13];
#pragma unroll
  for (int k = 0; k < 13; ++k) {
    w0[k] = W1[k * 128 + c0];
    w1[k] = W1[k * 128 + c1];
  }
  for (int node = wid; node <= N; node += nw) {
    if (node == N) { outb[(size_t)node * 64 + lane] = 0u; continue; }
    float4 A0 = *(const float4*)(ax + (size_t)node * 16);
    float4 A1 = *(const float4*)(ax + (size_t)node * 16 + 4);
    float4 A2 = *(const float4*)(ax + (size_t)node * 16 + 8);
    float  a12 = ax[(size_t)node * 16 + 12];
    float av[13] = {A0.x, A0.y, A0.z, A0.w, A1.x, A1.y, A1.z, A1.w,
                    A2.x, A2.y, A2.z, A2.w, a12};
    float acc0 = 0.f, acc1 = 0.f;
#pragma unroll
    for (int k = 0; k < 13; ++k) {
      acc0 = fmaf(av[k], w0[k], acc0);
      acc1 = fmaf(av[k], w1[k], acc1);
    }
    float dn = dis[node];
    float o0 = dn * fmaxf(fmaf(acc0, s0, t0), 0.f);
    float o1 = dn * fmaxf(fmaf(acc1, s1, t1), 0.f);
    outb[(size_t)node * 64 + lane] = pack2bf(o0, o1);
  }
}

// ---- 128-feat aggregation, quad scheme: 1 wave/node, 4 edges/step, uint4/lane ----
__global__ __launch_bounds__(256) void k_agg128(
    const u16* __restrict__ hb, const int* __restrict__ csr,
    const int* __restrict__ offs, const float* __restrict__ dis,
    uint4* __restrict__ Ahp, uint4* __restrict__ Alp, int N) {
  int node = (blockIdx.x << 2) + (threadIdx.x >> 6);
  if (node >= N) return;
  node = __builtin_amdgcn_readfirstlane(node);   // wave-uniform by construction
  const int lane = threadIdx.x & 63;
  const int qt = lane >> 4;      // edge slot within quad (0..3)
  const int q = lane & 15;       // uint4 slot = features 8q..8q+7
  const uint4* __restrict__ H = (const uint4*)hb;
  int beg = offs[node], end = offs[node + 1];    // multiple-of-4 segment

  float2 z2 = make_float2(0.f, 0.f);
  float2 aA0 = z2, aA1 = z2, aA2 = z2, aA3 = z2;
  float2 aB0 = z2, aB1 = z2, aB2 = z2, aB3 = z2;

  {
    uint4 su = H[(size_t)node * 16 + q];
    if (qt == 0) { dacc(aA0, su.x); dacc(aA1, su.y); dacc(aA2, su.z); dacc(aA3, su.w); }
  }

  int i = beg;
  for (; i + 8 <= end; i += 8) {
    int4 sA = *(const int4*)(csr + i);
    int4 sB = *(const int4*)(csr + i + 4);
    int ea = (qt == 0) ? sA.x : (qt == 1) ? sA.y : (qt == 2) ? sA.z : sA.w;
    int eb = (qt == 0) ? sB.x : (qt == 1) ? sB.y : (qt == 2) ? sB.z : sB.w;
    uint4 uA = H[(size_t)ea * 16 + q];
    uint4 uB = H[(size_t)eb * 16 + q];
    dacc(aA0, uA.x); dacc(aA1, uA.y); dacc(aA2, uA.z); dacc(aA3, uA.w);
    dacc(aB0, uB.x); dacc(aB1, uB.y); dacc(aB2, uB.z); dacc(aB3, uB.w);
  }
  if (i < end) {
    int4 sA = *(const int4*)(csr + i);
    int ea = (qt == 0) ? sA.x : (qt == 1) ? sA.y : (qt == 2) ? sA.z : sA.w;
    uint4 uA = H[(size_t)ea * 16 + q];
    dacc(aA0, uA.x); dacc(aA1, uA.y); dacc(aA2, uA.z); dacc(aA3, uA.w);
  }

  float r[8];
  r[0] = aA0.x + aB0.x; r[1] = aA0.y + aB0.y;
  r[2] = aA1.x + aB1.x; r[3] = aA1.y + aB1.y;
  r[4] = aA2.x + aB2.x; r[5] = aA2.y + aB2.y;
  r[6] = aA3.x + aB3.x; r[7] = aA3.y + aB3.y;
#pragma unroll
  for (int j = 0; j < 8; ++j) {
    r[j] += __shfl_xor(r[j], 16, 64);
    r[j] += __shfl_xor(r[j], 32, 64);
  }
  if (qt == 0) {
    float dn = dis[node];
    uint4 ph, pl;
    u32 hw[8];
#pragma unroll
    for (int j = 0; j < 8; ++j) { r[j] *= dn; hw[j] = f2bf(r[j]); }
    ph.x = hw[0] | (hw[1] << 16);
    ph.y = hw[2] | (hw[3] << 16);
    ph.z = hw[4] | (hw[5] << 16);
    ph.w = hw[6] | (hw[7] << 16);
    float l[8];
#pragma unroll
    for (int j = 0; j < 8; ++j) l[j] = r[j] - __uint_as_float(hw[j] << 16);
    pl.x = pack2bf(l[0], l[1]);
    pl.y = pack2bf(l[2], l[3]);
    pl.z = pack2bf(l[4], l[5]);
    pl.w = pack2bf(l[6], l[7]);
    Ahp[(size_t)node * 16 + q] = ph;
    Alp[(size_t)node * 16 + q] = pl;
  }
}

// ---- H x H GEMM via bf16x3-split MFMA (16x16x32), no LDS, 32 rows/wave ----
// MODE 0: out bf16 = dis*relu(...)  (hs for next layer)
// MODE 1: out bf16 = relu(...)      (h3, consumed by pooling)
template <int MODE>
__global__ __launch_bounds__(256) void k_gemm_mfma(
    const u16* __restrict__ Ah, const u16* __restrict__ Al,
    const u16* __restrict__ Wht, const u16* __restrict__ Wlt,
    const float* __restrict__ sc, const float* __restrict__ tc,
    const float* __restrict__ dis,
    u16* __restrict__ outb, int N) {
  const int lane = threadIdx.x & 63;
  const int wv = threadIdx.x >> 6;            // wave 0..3
  const int r0 = blockIdx.x * 128 + wv * 32;  // this wave: rows r0..r0+31
  const int lr = lane & 15;
  const int kg = lane >> 4;                   // k-group 0..3

  bf16x8 ahf[2][4], alf[2][4];
#pragma unroll
  for (int rt = 0; rt < 2; ++rt) {
    int row = min(r0 + rt * 16 + lr, N - 1);
    const bf16x8* pAh = (const bf16x8*)(Ah + (size_t)row * 128 + kg * 8);
    const bf16x8* pAl = (const bf16x8*)(Al + (size_t)row * 128 + kg * 8);
#pragma unroll
    for (int ks = 0; ks < 4; ++ks) {
      ahf[rt][ks] = pAh[ks * 4];
      alf[rt][ks] = pAl[ks * 4];
    }
  }
  float dr[2][4];
  if (MODE == 0) {
#pragma unroll
    for (int rt = 0; rt < 2; ++rt)
#pragma unroll
      for (int j = 0; j < 4; ++j)
        dr[rt][j] = dis[min(r0 + rt * 16 + kg * 4 + j, N - 1)];
  }

#pragma unroll
  for (int ct = 0; ct < 8; ++ct) {
    int c = ct * 16 + lr;
    const bf16x8* pBh = (const bf16x8*)(Wht + (size_t)c * 128 + kg * 8);
    const bf16x8* pBl = (const bf16x8*)(Wlt + (size_t)c * 128 + kg * 8);
    bf16x8 bh[4], bl[4];
#pragma unroll
    for (int ks = 0; ks < 4; ++ks) { bh[ks] = pBh[ks * 4]; bl[ks] = pBl[ks * 4]; }
    float s = sc[c], t = tc[c];
#pragma unroll
    for (int rt = 0; rt < 2; ++rt) {
      f32x4 acc = {0.f, 0.f, 0.f, 0.f};
#pragma unroll
      for (int ks = 0; ks < 4; ++ks) {
        acc = __builtin_amdgcn_mfma_f32_16x16x32_bf16(ahf[rt][ks], bh[ks], acc, 0, 0, 0);
        acc = __builtin_amdgcn_mfma_f32_16x16x32_bf16(alf[rt][ks], bh[ks], acc, 0, 0, 0);
        acc = __builtin_amdgcn_mfma_f32_16x16x32_bf16(ahf[rt][ks], bl[ks], acc, 0, 0, 0);
      }
      // C/D: col = lane&15, row = (lane>>4)*4 + j   [m89-verified]
#pragma unroll
      for (int j = 0; j < 4; ++j) {
        int row = r0 + rt * 16 + kg * 4 + j;
        if (row < N) {
          float o = fmaxf(fmaf(acc[j], s, t), 0.f);
          if (MODE == 0) o *= dr[rt][j];
          outb[(size_t)row * 128 + c] = (u16)f2bf(o);
        }
      }
    }
  }
}

// ---------------- pooling (bf16 input) + classifier ----------------
__global__ __launch_bounds__(128) void k_pool(
    const u16* __restrict__ hb, const int* __restrict__ batch,
    float* __restrict__ pooled, int N) {
  int f = threadIdx.x;
  int n0 = blockIdx.x * 128;
  int nEnd = min(n0 + 128, N);
  float acc = 0.f;
  int cur = -1;
  for (int nn = n0; nn < nEnd; ++nn) {
    int g = batch[nn];
    if (g != cur) {
      if (cur >= 0) atomicAdd(&pooled[cur * 128 + f], acc);
      cur = g;
      acc = 0.f;
    }
    acc += __uint_as_float((u32)hb[(size_t)nn * 128 + f] << 16);
  }
  if (cur >= 0) atomicAdd(&pooled[cur * 128 + f], acc);
}

__global__ __launch_bounds__(64) void k_cls(
    const float* __restrict__ pooled, const int* __restrict__ batch, int N,
    const float* __restrict__ Wc1, const float* __restrict__ bc1,
    const float* __restrict__ Wc2, const float* __restrict__ bc2,
    float* __restrict__ out, int G) {
  __shared__ float pm[128];
  __shared__ float hid[64];
  __shared__ float invc_s;
  int g = blockIdx.x, t = threadIdx.x;
  if (t == 0) {
    int lo = 0, hi = N;
    while (lo < hi) { int m = (lo + hi) >> 1; if (batch[m] < g) lo = m + 1; else hi = m; }
    int lb = lo;
    lo = 0; hi = N;
    while (lo < hi) { int m = (lo + hi) >> 1; if (batch[m] <= g) lo = m + 1; else hi = m; }
    invc_s = 1.f / fmaxf((float)(lo - lb), 1.f);
  }
  __syncthreads();
  float invc = invc_s;
  pm[t]      = pooled[g * 128 + t] * invc;
  pm[t + 64] = pooled[g * 128 + 64 + t] * invc;
  __syncthreads();
  float a = bc1[t];
#pragma unroll 8
  for (int k = 0; k < 128; ++k) a = fmaf(pm[k], Wc1[k * 64 + t], a);
  hid[t] = fmaxf(a, 0.f);
  __syncthreads();
  if (t < 10) {
    float a2 = bc2[t];
#pragma unroll
    for (int j = 0; j < 64; ++j) a2 = fmaf(hid[j], Wc2[j * 10 + t], a2);
    out[g * 10 + t] = a2;
  }
}

extern "C" void kernel_launch(void* const* d_in, const int* in_sizes, int n_in,
                              void* d_out, int out_size, void* d_ws, size_t ws_size,
                              hipStream_t stream) {
  const float* x   = (const float*)d_in[0];
  const int*   ei  = (const int*)d_in[1];
  const int* batch = (const int*)d_in[2];
  const float* W1 = (const float*)d_in[3];
  const float* b1 = (const float*)d_in[4];
  const float* g1 = (const float*)d_in[5];
  const float* be1 = (const float*)d_in[6];
  const float* m1 = (const float*)d_in[7];
  const float* v1 = (const float*)d_in[8];
  const float* W2 = (const float*)d_in[9];
  const float* b2 = (const float*)d_in[10];
  const float* g2 = (const float*)d_in[11];
  const float* be2 = (const float*)d_in[12];
  const float* m2 = (const float*)d_in[13];
  const float* v2 = (const float*)d_in[14];
  const float* W3 = (const float*)d_in[15];
  const float* b3 = (const float*)d_in[16];
  const float* g3 = (const float*)d_in[17];
  const float* be3 = (const float*)d_in[18];
  const float* m3 = (const float*)d_in[19];
  const float* v3 = (const float*)d_in[20];
  const float* Wc1 = (const float*)d_in[21];
  const float* bc1 = (const float*)d_in[22];
  const float* Wc2 = (const float*)d_in[23];
  const float* bc2 = (const float*)d_in[24];

  const int N = in_sizes[0] / 13;
  const int E = in_sizes[1] / 2;
  const int G = out_size / 10;
  const int* src = ei;
  const int* dst = ei + E;

  char* ws = (char*)d_ws;
  size_t off = 0;
  auto alloc = [&](size_t bytes) {
    char* p = ws + off;
    off = (off + bytes + 255) & ~(size_t)255;
    return p;
  };
  int*   deg    = (int*)  alloc((size_t)N * 4);
  float* dis    = (float*)alloc((size_t)N * 4);
  int*   pdeg   = (int*)  alloc((size_t)N * 4);
  int*   offs   = (int*)  alloc((size_t)(N + 1) * 4);
  const int nb  = (N + 255) / 256;
  int*   bsum   = (int*)  alloc((size_t)nb * 4);
  int*   bexc   = (int*)  alloc((size_t)nb * 4);
  int*   rank   = (int*)  alloc((size_t)E * 4);
  int*   csr    = (int*)  alloc(((size_t)E + 3 * (size_t)N + 8) * 4);
  u16*   hbf    = (u16*)  alloc((size_t)(N + 1) * 128 * 2);   // hs bf16 / later h3 bf16
  u16*   Ahp    = (u16*)  alloc((size_t)N * 128 * 2);         // agg out hi
  u16*   Alp    = (u16*)  alloc((size_t)N * 128 * 2);         // agg out lo residual
  float* xs     = (float*)alloc((size_t)(N + 1) * 16 * 4);    // scaled padded x
  u16*   Wht2   = (u16*)  alloc(16384 * 2);
  u16*   Wlt2   = (u16*)  alloc(16384 * 2);
  u16*   Wht3   = (u16*)  alloc(16384 * 2);
  u16*   Wlt3   = (u16*)  alloc(16384 * 2);
  float* sc2    = (float*)alloc(128 * 4);
  float* tc2    = (float*)alloc(128 * 4);
  float* sc3    = (float*)alloc(128 * 4);
  float* tc3    = (float*)alloc(128 * 4);
  float* pooled = (float*)alloc((size_t)G * 128 * 4);
  float* ax = (float*)Ahp;   // [N,16] alias (consumed before agg128 writes Ahp)

  // prep_w also zeroes deg, pooled, and hbf's pad row (row N)
  k_prep_w<<<128, 256, 0, stream>>>(W2, W3, b2, g2, be2, m2, v2, b3, g3, be3, m3, v3,
                                    Wht2, Wlt2, Wht3, Wlt3, sc2, tc2, sc3, tc3,
                                    deg, pooled, (u32*)(hbf + (size_t)N * 128),
                                    N, G * 128);

  const int nE8 = (E + 7) / 8;
  k_hist_rank<<<(nE8 + 255) / 256, 256, 0, stream>>>(dst, deg, rank, E);
  k_prep_nodes<<<(N + 256) / 256, 256, 0, stream>>>(deg, x, dis, pdeg, xs, N);
  k_scan_block<<<nb, 256, 0, stream>>>(pdeg, offs, bsum, N);
  k_scan_bsum<<<1, 512, 0, stream>>>(bsum, bexc, nb);
  k_add_back_pad<<<nb, 256, 0, stream>>>(offs, bexc, bsum, deg, pdeg, csr, N, nb);
  const int nE4 = (E + 3) / 4;
  k_fill_rank<<<(nE4 + 255) / 256, 256, 0, stream>>>(src, dst, rank, offs, csr, E);

  k_agg16<<<(N + 3) / 4, 64, 0, stream>>>(xs, csr, offs, dis, ax, N);
  k_gemm1<<<1024, 256, 0, stream>>>(ax, W1, b1, g1, be1, m1, v1, dis, (u32*)hbf, N);

  const int gemmGrid = (N + 127) / 128;
  k_agg128<<<(N + 3) / 4, 256, 0, stream>>>(hbf, csr, offs, dis,
                                            (uint4*)Ahp, (uint4*)Alp, N);
  k_gemm_mfma<0><<<gemmGrid, 256, 0, stream>>>(Ahp, Alp, Wht2, Wlt2, sc2, tc2, dis,
                                               hbf, N);
  k_agg128<<<(N + 3) / 4, 256, 0, stream>>>(hbf, csr, offs, dis,
                                            (uint4*)Ahp, (uint4*)Alp, N);
  k_gemm_mfma<1><<<gemmGrid, 256, 0, stream>>>(Ahp, Alp, Wht3, Wlt3, sc3, tc3, dis,
                                               hbf, N);

  k_pool<<<(N + 127) / 128, 128, 0, stream>>>(hbf, batch, pooled, N);
  k_cls<<<G, 64, 0, stream>>>(pooled, batch, N, Wc1, bc1, Wc2, bc2, (float*)d_out, G);
}